// Round 1
// baseline (1366.059 us; speedup 1.0000x reference)
//
#include <hip/hip_runtime.h>

namespace {
constexpr int kK = 8;      // children
constexpr int kD = 128;    // input dim
constexpr int kH = 128;    // hidden dim
constexpr int kM = 16;     // nodes per block
constexpr int kBlk = 256;  // threads per block
}

__device__ __forceinline__ float sig_(float z) {
  return 1.0f / (1.0f + __expf(-z));
}
__device__ __forceinline__ float th_(float z) {
  // tanh(z) = 1 - 2/(exp(2z)+1); saturates correctly for large |z|
  return 1.0f - 2.0f / (__expf(2.0f * z) + 1.0f);
}
__device__ __forceinline__ void fma4_(float* a, float s, const float4& v) {
  a[0] = fmaf(s, v.x, a[0]);
  a[1] = fmaf(s, v.y, a[1]);
  a[2] = fmaf(s, v.z, a[2]);
  a[3] = fmaf(s, v.w, a[3]);
}

__global__ __launch_bounds__(kBlk) void treelstm_fused(
    const float* __restrict__ x, const float* __restrict__ child_h,
    const float* __restrict__ child_c, const float* __restrict__ Wi,
    const float* __restrict__ bi, const float* __restrict__ Ui,
    const float* __restrict__ Wo, const float* __restrict__ bo,
    const float* __restrict__ Uo, const float* __restrict__ Wu,
    const float* __restrict__ bu, const float* __restrict__ Uu,
    const float* __restrict__ Wf, const float* __restrict__ bf,
    const float* __restrict__ Uf, float* __restrict__ h_out,
    float* __restrict__ c_out) {
  __shared__ float xs[kM][kD];  // x tile
  __shared__ float hs[kM][kH];  // h_sum tile

  const int t = threadIdx.x;
  const int n0 = blockIdx.x * kM;

  // ---- Phase 1: stage x tile (512 float4, 2 per thread, coalesced) ----
  {
    const float4* xg = reinterpret_cast<const float4*>(x + (size_t)n0 * kD);
    float4* xsv = reinterpret_cast<float4*>(&xs[0][0]);
    xsv[t] = xg[t];
    xsv[t + kBlk] = xg[t + kBlk];
  }
  // ---- Phase 2: h_sum tile (coalesced float4 over d, loop k) ----
  {
    float4* hsv = reinterpret_cast<float4*>(&hs[0][0]);
#pragma unroll
    for (int r = 0; r < 2; ++r) {
      const int q = t + r * kBlk;  // float4 index into [kM][kH]
      const int m = q >> 5;        // 32 float4 per node row
      const int dq = q & 31;
      const float4* chg = reinterpret_cast<const float4*>(
                              child_h + (size_t)(n0 + m) * (kK * kH)) + dq;
      float4 s = chg[0];
#pragma unroll
      for (int k = 1; k < kK; ++k) {
        const float4 v = chg[k * (kH / 4)];
        s.x += v.x; s.y += v.y; s.z += v.z; s.w += v.w;
      }
      hsv[q] = s;
    }
  }
  __syncthreads();

  // thread owns nodes (m1, m2) x output columns j0..j0+3
  const int jq = t & 31;
  const int j0 = jq * 4;
  const int mg = t >> 5;
  const int m1 = mg;
  const int m2 = mg + 8;
  const size_t nrow1 = (size_t)(n0 + m1);
  const size_t nrow2 = (size_t)(n0 + m2);

  // ---- Phase 3: 7 fused GEMVs (Wi,Wo,Wu,Wf with x; Ui,Uo,Uu with h_sum) ----
  float acc[7][2][4];
#pragma unroll
  for (int g = 0; g < 7; ++g)
#pragma unroll
    for (int p = 0; p < 2; ++p)
#pragma unroll
      for (int c = 0; c < 4; ++c) acc[g][p][c] = 0.0f;

#pragma unroll 2
  for (int d = 0; d < kD; ++d) {
    const float xv1 = xs[m1][d], xv2 = xs[m2][d];
    const float hv1 = hs[m1][d], hv2 = hs[m2][d];
    const int off = d * kH + j0;
    const float4 wi = *reinterpret_cast<const float4*>(Wi + off);
    const float4 wo = *reinterpret_cast<const float4*>(Wo + off);
    const float4 wu = *reinterpret_cast<const float4*>(Wu + off);
    const float4 wf = *reinterpret_cast<const float4*>(Wf + off);
    const float4 ui = *reinterpret_cast<const float4*>(Ui + off);
    const float4 uo = *reinterpret_cast<const float4*>(Uo + off);
    const float4 uu = *reinterpret_cast<const float4*>(Uu + off);
    fma4_(acc[0][0], xv1, wi); fma4_(acc[0][1], xv2, wi);
    fma4_(acc[1][0], xv1, wo); fma4_(acc[1][1], xv2, wo);
    fma4_(acc[2][0], xv1, wu); fma4_(acc[2][1], xv2, wu);
    fma4_(acc[3][0], xv1, wf); fma4_(acc[3][1], xv2, wf);
    fma4_(acc[4][0], hv1, ui); fma4_(acc[4][1], hv2, ui);
    fma4_(acc[5][0], hv1, uo); fma4_(acc[5][1], hv2, uo);
    fma4_(acc[6][0], hv1, uu); fma4_(acc[6][1], hv2, uu);
  }

  const float4 bi4 = *reinterpret_cast<const float4*>(bi + j0);
  const float4 bo4 = *reinterpret_cast<const float4*>(bo + j0);
  const float4 bu4 = *reinterpret_cast<const float4*>(bu + j0);
  const float4 bf4 = *reinterpret_cast<const float4*>(bf + j0);
  const float bia[4] = {bi4.x, bi4.y, bi4.z, bi4.w};
  const float boa[4] = {bo4.x, bo4.y, bo4.z, bo4.w};
  const float bua[4] = {bu4.x, bu4.y, bu4.z, bu4.w};
  const float bfa[4] = {bf4.x, bf4.y, bf4.z, bf4.w};

  float iu[2][4], og[2][4], fx[2][4];
#pragma unroll
  for (int p = 0; p < 2; ++p)
#pragma unroll
    for (int c = 0; c < 4; ++c) {
      const float ig = sig_(acc[0][p][c] + acc[4][p][c] + bia[c]);
      const float o  = sig_(acc[1][p][c] + acc[5][p][c] + boa[c]);
      const float ug = th_ (acc[2][p][c] + acc[6][p][c] + bua[c]);
      iu[p][c] = ig * ug;   // i * u
      og[p][c] = o;
      fx[p][c] = acc[3][p][c] + bfa[c];  // x@Wf + bf preact
    }

  // ---- Phase 4: per-child forget gates + c accumulation ----
  const float* chb1 = child_h + nrow1 * (kK * kH);
  const float* chb2 = child_h + nrow2 * (kK * kH);
  const float* ccb1 = child_c + nrow1 * (kK * kH);
  const float* ccb2 = child_c + nrow2 * (kK * kH);

  float cacc[2][4];
#pragma unroll
  for (int p = 0; p < 2; ++p)
#pragma unroll
    for (int c = 0; c < 4; ++c) cacc[p][c] = 0.0f;

#pragma unroll
  for (int kh = 0; kh < 2; ++kh) {  // two halves of k to bound VGPRs
    const int kb = kh * 4;
    float fpre[2][4][4];
#pragma unroll
    for (int p = 0; p < 2; ++p)
#pragma unroll
      for (int kk = 0; kk < 4; ++kk)
#pragma unroll
        for (int c = 0; c < 4; ++c) fpre[p][kk][c] = fx[p][c];

    for (int d0 = 0; d0 < kD; d0 += 4) {
      const float4 uf0 = *reinterpret_cast<const float4*>(Uf + (d0 + 0) * kH + j0);
      const float4 uf1 = *reinterpret_cast<const float4*>(Uf + (d0 + 1) * kH + j0);
      const float4 uf2 = *reinterpret_cast<const float4*>(Uf + (d0 + 2) * kH + j0);
      const float4 uf3 = *reinterpret_cast<const float4*>(Uf + (d0 + 3) * kH + j0);
#pragma unroll
      for (int kk = 0; kk < 4; ++kk) {
        const float4 c1 = *reinterpret_cast<const float4*>(chb1 + (kb + kk) * kH + d0);
        const float4 c2 = *reinterpret_cast<const float4*>(chb2 + (kb + kk) * kH + d0);
        fma4_(fpre[0][kk], c1.x, uf0); fma4_(fpre[0][kk], c1.y, uf1);
        fma4_(fpre[0][kk], c1.z, uf2); fma4_(fpre[0][kk], c1.w, uf3);
        fma4_(fpre[1][kk], c2.x, uf0); fma4_(fpre[1][kk], c2.y, uf1);
        fma4_(fpre[1][kk], c2.z, uf2); fma4_(fpre[1][kk], c2.w, uf3);
      }
    }

#pragma unroll
    for (int kk = 0; kk < 4; ++kk) {
      const int k = kb + kk;
      const float4 cc1 = *reinterpret_cast<const float4*>(ccb1 + k * kH + j0);
      const float4 cc2 = *reinterpret_cast<const float4*>(ccb2 + k * kH + j0);
      const float cc1a[4] = {cc1.x, cc1.y, cc1.z, cc1.w};
      const float cc2a[4] = {cc2.x, cc2.y, cc2.z, cc2.w};
#pragma unroll
      for (int c = 0; c < 4; ++c) {
        cacc[0][c] = fmaf(sig_(fpre[0][kk][c]), cc1a[c], cacc[0][c]);
        cacc[1][c] = fmaf(sig_(fpre[1][kk][c]), cc2a[c], cacc[1][c]);
      }
    }
  }

  // ---- Phase 5: c = i*u + sum_k f_k*c_k ; h = o * tanh(c) ----
#pragma unroll
  for (int p = 0; p < 2; ++p) {
    const size_t nr = (p == 0) ? nrow1 : nrow2;
    float cvals[4], hvals[4];
#pragma unroll
    for (int c = 0; c < 4; ++c) {
      const float cv = iu[p][c] + cacc[p][c];
      cvals[c] = cv;
      hvals[c] = og[p][c] * th_(cv);
    }
    *reinterpret_cast<float4*>(h_out + nr * kH + j0) =
        make_float4(hvals[0], hvals[1], hvals[2], hvals[3]);
    *reinterpret_cast<float4*>(c_out + nr * kH + j0) =
        make_float4(cvals[0], cvals[1], cvals[2], cvals[3]);
  }
}

extern "C" void kernel_launch(void* const* d_in, const int* in_sizes, int n_in,
                              void* d_out, int out_size, void* d_ws,
                              size_t ws_size, hipStream_t stream) {
  const float* x       = (const float*)d_in[0];
  const float* child_h = (const float*)d_in[1];
  const float* child_c = (const float*)d_in[2];
  const float* Wi = (const float*)d_in[3];
  const float* bi = (const float*)d_in[4];
  const float* Ui = (const float*)d_in[5];
  const float* Wo = (const float*)d_in[6];
  const float* bo = (const float*)d_in[7];
  const float* Uo = (const float*)d_in[8];
  const float* Wu = (const float*)d_in[9];
  const float* bu = (const float*)d_in[10];
  const float* Uu = (const float*)d_in[11];
  const float* Wf = (const float*)d_in[12];
  const float* bf = (const float*)d_in[13];
  const float* Uf = (const float*)d_in[14];

  const int n = in_sizes[0] / kD;  // 65536
  float* h_out = (float*)d_out;
  float* c_out = (float*)d_out + (size_t)n * kH;

  dim3 grid(n / kM), block(kBlk);
  treelstm_fused<<<grid, block, 0, stream>>>(x, child_h, child_c, Wi, bi, Ui,
                                             Wo, bo, Uo, Wu, bu, Uu, Wf, bf,
                                             Uf, h_out, c_out);
}